// Round 5
// baseline (49.800 us; speedup 1.0000x reference)
//
#include <hip/hip_runtime.h>

// Problem constants
#define BB 4
#define LL 512
#define WW 256
#define EE 300
#define HH 768

typedef __attribute__((ext_vector_type(8))) short bf16x8;
typedef __attribute__((ext_vector_type(4))) float f32x4;

__device__ __forceinline__ short f2bf(float f) {
    union { float f; unsigned u; } v; v.f = f;
    unsigned r = (v.u + 0x7FFFu + ((v.u >> 16) & 1u)) >> 16;
    return (short)r;
}

// Device-wide barrier. Safe only because grid (256 blocks, <=47KB LDS,
// 4 waves) is fully co-resident on 256 CUs. cnt/flag zeroed by
// hipMemsetAsync before every launch -> deterministic across replays.
__device__ __forceinline__ void grid_barrier(int* cnt, int* flag, int nblocks) {
    __syncthreads();
    if (threadIdx.x == 0) {
        __threadfence();   // release my global writes to the coherence point
        const int old = __hip_atomic_fetch_add(cnt, 1, __ATOMIC_ACQ_REL,
                                               __HIP_MEMORY_SCOPE_AGENT);
        if (old == nblocks - 1) {
            __hip_atomic_store(flag, 1, __ATOMIC_RELEASE, __HIP_MEMORY_SCOPE_AGENT);
        } else {
            while (__hip_atomic_load(flag, __ATOMIC_RELAXED,
                                     __HIP_MEMORY_SCOPE_AGENT) == 0) {
                __builtin_amdgcn_s_sleep(2);
            }
        }
        __threadfence();   // acquire side
    }
    __syncthreads();
}

// ---------------------------------------------------------------------------
// Single kernel, 256 blocks x 256 threads.
// Phase A (blocks 0..191): aT = (emb_a[word_seq] @ lin_w + lin_b), bf16,
//   k-major layout aT[b][h/8][w][h%8]; 64m x 64n tiles, double-buffered LDS,
//   one barrier per k-step (R4-verified body).
// All blocks: stage their Phase-B hidden tile (8 real rows + 8 zero rows).
// grid_barrier.
// Phase B (all 256): 8 l-rows each: u = hid @ aT^T (24 unrolled k-steps,
//   coalesced 16B B-frag global loads, no barriers), exp/label-bucket sums,
//   fused output o = (sum_c s_c*emb_c[c]) / (sum + 1e-10).
// ---------------------------------------------------------------------------
__global__ __launch_bounds__(256) void fused_gca(
    const int*   __restrict__ word_seq,
    const float* __restrict__ hidden,
    const int*   __restrict__ label,
    const float* __restrict__ emb_a,
    const float* __restrict__ lin_w,
    const float* __restrict__ lin_b,
    const float* __restrict__ emb_c,
    float*       __restrict__ out,
    short*       __restrict__ aT,      // ws: [4][96][256][8] bf16
    int*         __restrict__ bar)     // ws: {cnt, pad..., flag at +32}
{
    __shared__ short ea[2][64 * 40];
    __shared__ short lw[2][64 * 40];
    __shared__ int   word[64];
    __shared__ short hid[16 * 776];
    __shared__ float s_lds[4][16][5];
    __shared__ float s_fin[16][5];
    __shared__ float invd[16];

    const int bid = blockIdx.x;
    const int t   = threadIdx.x;
    const int lane = t & 63, wv = t >> 6;
    const int l15 = lane & 15, l4 = lane >> 4;

    // ================= Phase A: a GEMM (blocks 0..191) =================
    if (bid < 192) {
        const int m0 = (bid & 15) * 64;
        const int n0 = (bid >> 4) * 64;

        if (t < 64) word[t] = word_seq[m0 + t];
        __syncthreads();

        const int r_ea  = t >> 2;          // 0..63 m-row
        const int ec    = (t & 3) * 8;     // k-chunk within 32
        const int h_lw  = t & 63;          // n-row
        const int kc_lw = (t >> 6) * 8;    // k-chunk within 32

        const long ea_base = (long)word[r_ea] * EE + ec;

        float ea_reg[8], lw_reg[8];
        {
#pragma unroll
            for (int j = 0; j < 8; j += 2) {
                const float2 p = *(const float2*)(emb_a + ea_base + j);
                ea_reg[j] = p.x; ea_reg[j + 1] = p.y;
            }
#pragma unroll
            for (int j = 0; j < 8; ++j)
                lw_reg[j] = lin_w[(long)(kc_lw + j) * HH + n0 + h_lw];
        }

        f32x4 acc[4] = {};

#pragma unroll
        for (int it = 0; it < 10; ++it) {
            const int cur = it & 1;
            {
                bf16x8 sv;
#pragma unroll
                for (int j = 0; j < 8; ++j) sv[j] = f2bf(ea_reg[j]);
                *(bf16x8*)(&ea[cur][r_ea * 40 + ec]) = sv;
#pragma unroll
                for (int j = 0; j < 8; ++j) sv[j] = f2bf(lw_reg[j]);
                *(bf16x8*)(&lw[cur][h_lw * 40 + kc_lw]) = sv;
            }
            __syncthreads();
            if (it < 9) {
                const int e0 = (it + 1) * 32;
#pragma unroll
                for (int j = 0; j < 8; j += 2) {
                    const int e = e0 + ec + j;
                    if (e < EE) {
                        const float2 p = *(const float2*)(emb_a + ea_base + e0 + j);
                        ea_reg[j] = p.x; ea_reg[j + 1] = p.y;
                    } else { ea_reg[j] = 0.f; ea_reg[j + 1] = 0.f; }
                }
#pragma unroll
                for (int j = 0; j < 8; ++j) {
                    const int e = e0 + kc_lw + j;
                    lw_reg[j] = (e < EE) ? lin_w[(long)e * HH + n0 + h_lw] : 0.f;
                }
            }
            {
                const bf16x8 af = *(const bf16x8*)(&ea[cur][(wv * 16 + l15) * 40 + l4 * 8]);
#pragma unroll
                for (int nf = 0; nf < 4; ++nf) {
                    const bf16x8 bfv = *(const bf16x8*)(&lw[cur][(nf * 16 + l15) * 40 + l4 * 8]);
                    acc[nf] = __builtin_amdgcn_mfma_f32_16x16x32_bf16(af, bfv, acc[nf], 0, 0, 0);
                }
            }
        }

        // epilogue: bias + bf16 store to aT[b][h/8][w][h%8]
        const int b1 = m0 >> 8;
#pragma unroll
        for (int nf = 0; nf < 4; ++nf) {
            const int h    = n0 + nf * 16 + l15;
            const float bv = lin_b[h];
            const long hbase = ((long)(b1 * 96 + (h >> 3)) * 256) * 8 + (h & 7);
#pragma unroll
            for (int i = 0; i < 4; ++i) {
                const int w = (m0 & 255) + wv * 16 + l4 * 4 + i;
                aT[hbase + (long)w * 8] = f2bf(acc[nf][i] + bv);
            }
        }
    }

    // ---- all blocks: stage Phase-B hidden tile (8 real rows + 8 zero) ----
    const int row0 = bid * 8;             // flat (b*512 + l) base
    const int b    = row0 >> 9;
    {
        const float* hrow = hidden + (long)row0 * HH;
#pragma unroll
        for (int j = 0; j < 3; ++j) {
            const int idx = (t + j * 256) * 8;      // < 6144
            const int row = idx / HH;
            const int col = idx - row * HH;
            const float4 p0 = *(const float4*)(hrow + idx);
            const float4 p1 = *(const float4*)(hrow + idx + 4);
            bf16x8 v;
            v[0] = f2bf(p0.x); v[1] = f2bf(p0.y); v[2] = f2bf(p0.z); v[3] = f2bf(p0.w);
            v[4] = f2bf(p1.x); v[5] = f2bf(p1.y); v[6] = f2bf(p1.z); v[7] = f2bf(p1.w);
            *(bf16x8*)(&hid[row * 776 + col]) = v;
        }
        const bf16x8 z = {};
#pragma unroll
        for (int j = 0; j < 3; ++j) {
            const int idx = (t + j * 256) * 8;
            const int row = idx / HH;
            const int col = idx - row * HH;
            *(bf16x8*)(&hid[(8 + row) * 776 + col]) = z;
        }
    }

    grid_barrier(bar, bar + 8, 256);

    // ================= Phase B: u GEMM + buckets + output =================
    {
        const short* abase = aT + (long)b * 96 * 256 * 8;
        f32x4 acc[4] = {};
#pragma unroll
        for (int ks = 0; ks < 24; ++ks) {
            const bf16x8 af = *(const bf16x8*)(&hid[l15 * 776 + ks * 32 + l4 * 8]);
#pragma unroll
            for (int nf = 0; nf < 4; ++nf) {
                const int w = wv * 64 + nf * 16 + l15;
                const bf16x8 bfv =
                    *(const bf16x8*)(abase + ((long)(ks * 4 + l4) * 256 + w) * 8);
                acc[nf] = __builtin_amdgcn_mfma_f32_16x16x32_bf16(af, bfv, acc[nf], 0, 0, 0);
            }
        }

        const float inv_temper = 0.03608439182435161f;   // 1/sqrt(768)
        float s_loc[4][5];
#pragma unroll
        for (int i = 0; i < 4; ++i)
#pragma unroll
            for (int c = 0; c < 5; ++c) s_loc[i][c] = 0.f;

        const int* lab_base = label + (long)row0 * WW;
#pragma unroll
        for (int nf = 0; nf < 4; ++nf) {
            const int w = wv * 64 + nf * 16 + l15;
#pragma unroll
            for (int i = 0; i < 4; ++i) {
                const int row = l4 * 4 + i;              // 0..15; real if <8
                const int lv  = (row < 8) ? lab_base[row * WW + w] : 0;
                const float e = __expf(acc[nf][i] * inv_temper);
#pragma unroll
                for (int c = 1; c <= 5; ++c)
                    s_loc[i][c - 1] += (lv == c) ? e : 0.f;
            }
        }
#pragma unroll
        for (int i = 0; i < 4; ++i) {
#pragma unroll
            for (int c = 0; c < 5; ++c) {
                float v = s_loc[i][c];
                v += __shfl_xor(v, 1);
                v += __shfl_xor(v, 2);
                v += __shfl_xor(v, 4);
                v += __shfl_xor(v, 8);
                s_loc[i][c] = v;
            }
        }
        if (l15 == 0) {
#pragma unroll
            for (int i = 0; i < 4; ++i)
#pragma unroll
                for (int c = 0; c < 5; ++c)
                    s_lds[wv][l4 * 4 + i][c] = s_loc[i][c];
        }
        __syncthreads();
        if (t < 8) {
            float den = 0.f;
#pragma unroll
            for (int c = 0; c < 5; ++c) {
                const float s = s_lds[0][t][c] + s_lds[1][t][c] +
                                s_lds[2][t][c] + s_lds[3][t][c];
                s_fin[t][c] = s;
                den += s;
            }
            invd[t] = 1.0f / (den + 1e-10f);
        }
        __syncthreads();

        float ecv[3][5];
#pragma unroll
        for (int q = 0; q < 3; ++q)
#pragma unroll
            for (int c = 0; c < 5; ++c)
                ecv[q][c] = emb_c[(c + 1) * HH + t + q * 256];

        float* obase = out + (long)row0 * HH;
        for (int row = 0; row < 8; ++row) {
            const float id = invd[row];
            const float s0 = s_fin[row][0], s1 = s_fin[row][1], s2 = s_fin[row][2],
                        s3 = s_fin[row][3], s4 = s_fin[row][4];
#pragma unroll
            for (int q = 0; q < 3; ++q) {
                const float v = s0 * ecv[q][0] + s1 * ecv[q][1] + s2 * ecv[q][2] +
                                s3 * ecv[q][3] + s4 * ecv[q][4];
                obase[(long)row * HH + t + q * 256] = v * id;
            }
        }
    }
}

extern "C" void kernel_launch(void* const* d_in, const int* in_sizes, int n_in,
                              void* d_out, int out_size, void* d_ws, size_t ws_size,
                              hipStream_t stream) {
    const int*   word_seq = (const int*)  d_in[0];
    const float* hidden   = (const float*)d_in[1];
    const int*   label    = (const int*)  d_in[2];
    const float* emb_a    = (const float*)d_in[3];
    const float* lin_w    = (const float*)d_in[4];
    const float* lin_b    = (const float*)d_in[5];
    const float* emb_c    = (const float*)d_in[6];
    float* out = (float*)d_out;

    short* aT  = (short*)d_ws;                          // 1.5 MB
    int*   bar = (int*)((char*)d_ws + 0x180000);        // cnt @+0, flag @+32

    hipMemsetAsync((void*)bar, 0, 256, stream);         // reset barrier state
    fused_gca<<<dim3(256), 256, 0, stream>>>(word_seq, hidden, label, emb_a,
                                             lin_w, lin_b, emb_c, out, aT, bar);
}

// Round 6
// 24.130 us; speedup vs baseline: 2.0638x; 2.0638x over previous
//
#include <hip/hip_runtime.h>

// Problem constants
#define BB 4
#define LL 512
#define WW 256
#define EE 300
#define HH 768

typedef __attribute__((ext_vector_type(8))) short bf16x8;
typedef __attribute__((ext_vector_type(4))) float f32x4;

__device__ __forceinline__ short f2bf(float f) {
    union { float f; unsigned u; } v; v.f = f;
    unsigned r = (v.u + 0x7FFFu + ((v.u >> 16) & 1u)) >> 16;
    return (short)r;
}

// ---------------------------------------------------------------------------
// k1: aT = (emb_a[word_seq] @ lin_w + lin_b), bf16, k-major aT[b][h/8][w][h%8].
// 192 blocks x 256 thr, tile 64m x 64n. K=320 (zero-pad past 300) split into
// TWO mega-steps of 160: per step every thread's global loads are mutually
// independent (issue together, one latency), pack to step-private LDS, one
// barrier, 20 MFMA. Step-1 loads are issued before step-0 MFMA -> overlap.
// launch_bounds(256,1): VGPR budget 512 so the compiler keeps loads in flight.
// ---------------------------------------------------------------------------
__global__ __launch_bounds__(256, 1) void k1_a_gemm(
    const int*   __restrict__ word_seq,
    const float* __restrict__ emb_a,
    const float* __restrict__ lin_w,
    const float* __restrict__ lin_b,
    short*       __restrict__ aT)      // [4][96][256][8] bf16
{
    __shared__ short eaL[2][64 * 168];   // [half][m-row][k] bf16, stride 168
    __shared__ short lwL[2][64 * 168];   // [half][n-row(h)][k]

    const int t  = threadIdx.x;
    const int m0 = (blockIdx.x & 15) * 64;
    const int n0 = (blockIdx.x >> 4) * 64;

    const int lane = t & 63, wv = t >> 6;
    const int l15 = lane & 15, l4 = lane >> 4;

    // load/pack coords
    const int r_ea = t >> 2;             // 0..63 m-row
    const int q_ea = t & 3;              // quarter of the 160-wide half
    const int h_lw = t & 63;             // n-row
    const int q_lw = t >> 6;             // quarter

    const int  wrow    = word_seq[m0 + r_ea];
    const float* arow  = emb_a + (long)wrow * EE;

    f32x4 acc[4] = {};

    float ea_reg[40], lw_reg[40];

#pragma unroll
    for (int half = 0; half < 2; ++half) {
        const int k0 = half * 160;
        // ---- issue this half's loads (all independent) ----
        {
            const int cbase = k0 + q_ea * 40;
#pragma unroll
            for (int c4 = 0; c4 < 10; ++c4) {
                const int col = cbase + c4 * 4;
                if (col <= 296) {        // full float4 real (E=300, col%4==0)
                    const float4 p = *(const float4*)(arow + col);
                    ea_reg[c4 * 4 + 0] = p.x; ea_reg[c4 * 4 + 1] = p.y;
                    ea_reg[c4 * 4 + 2] = p.z; ea_reg[c4 * 4 + 3] = p.w;
                } else {
                    ea_reg[c4 * 4 + 0] = 0.f; ea_reg[c4 * 4 + 1] = 0.f;
                    ea_reg[c4 * 4 + 2] = 0.f; ea_reg[c4 * 4 + 3] = 0.f;
                }
            }
            const int cb2 = k0 + q_lw * 40;
#pragma unroll
            for (int j = 0; j < 40; ++j) {
                const int col = cb2 + j;
                lw_reg[j] = (col < EE) ? lin_w[(long)col * HH + n0 + h_lw] : 0.f;
            }
        }
        // ---- pack to LDS ----
        {
            const int eoff = r_ea * 168 + q_ea * 40;
#pragma unroll
            for (int c8 = 0; c8 < 5; ++c8) {
                bf16x8 sv;
#pragma unroll
                for (int j = 0; j < 8; ++j) sv[j] = f2bf(ea_reg[c8 * 8 + j]);
                *(bf16x8*)(&eaL[half][eoff + c8 * 8]) = sv;
            }
            const int loff = h_lw * 168 + q_lw * 40;
#pragma unroll
            for (int c8 = 0; c8 < 5; ++c8) {
                bf16x8 sv;
#pragma unroll
                for (int j = 0; j < 8; ++j) sv[j] = f2bf(lw_reg[c8 * 8 + j]);
                *(bf16x8*)(&lwL[half][loff + c8 * 8]) = sv;
            }
        }
        __syncthreads();
        // ---- MFMA on this half (5 k-steps x 4 n-frags) ----
#pragma unroll
        for (int ks = 0; ks < 5; ++ks) {
            const bf16x8 af =
                *(const bf16x8*)(&eaL[half][(wv * 16 + l15) * 168 + ks * 32 + l4 * 8]);
#pragma unroll
            for (int nf = 0; nf < 4; ++nf) {
                const bf16x8 bfv =
                    *(const bf16x8*)(&lwL[half][(nf * 16 + l15) * 168 + ks * 32 + l4 * 8]);
                acc[nf] = __builtin_amdgcn_mfma_f32_16x16x32_bf16(af, bfv, acc[nf], 0, 0, 0);
            }
        }
    }

    // ---- epilogue: bias + bf16 store to aT[b][h/8][w][h%8] ----
    const int b1 = m0 >> 8;
#pragma unroll
    for (int nf = 0; nf < 4; ++nf) {
        const int h    = n0 + nf * 16 + l15;
        const float bv = lin_b[h];
        const long hbase = ((long)(b1 * 96 + (h >> 3)) * 256) * 8 + (h & 7);
#pragma unroll
        for (int i = 0; i < 4; ++i) {
            const int w = (m0 & 255) + wv * 16 + l4 * 4 + i;
            aT[hbase + (long)w * 8] = f2bf(acc[nf][i] + bv);
        }
    }
}

// ---------------------------------------------------------------------------
// k2: block = (16 l-rows, half of w). u = hid @ aT^T (24 unrolled k-steps,
// nf=2 -> 48-deep independent coalesced B-load chain per wave), exp +
// label-bucket partial sums -> s_part[row][whalf*5 + c].
// 256 blocks x 256 thr (full GPU), launch_bounds(256,1) for deep pipelining.
// ---------------------------------------------------------------------------
__global__ __launch_bounds__(256, 1) void k2_attn(
    const float* __restrict__ hidden,   // [4][512][768] f32
    const int*   __restrict__ label,    // [4][512][256]
    const short* __restrict__ aT,       // [4][96][256][8] bf16
    float*       __restrict__ s_part)   // [2048][10] f32
{
    __shared__ short hid[16 * 776];
    __shared__ float s_lds[4][16][5];

    const int t = threadIdx.x, lane = t & 63, wv = t >> 6;
    const int l15 = lane & 15, l4 = lane >> 4;
    const int blt   = blockIdx.x >> 1;
    const int whalf = blockIdx.x & 1;
    const int bl0   = blt * 16;
    const int b     = bl0 >> 9;
    const int w0    = whalf * 128;

    // ---- stage hidden tile -> bf16 LDS (vectorized) ----
    {
        const float* hrow = hidden + (long)bl0 * HH;
#pragma unroll
        for (int j = 0; j < 6; ++j) {
            const int idx = (t + j * 256) * 8;      // 8 | 768
            const int row = idx / HH;
            const int col = idx - row * HH;
            const float4 p0 = *(const float4*)(hrow + idx);
            const float4 p1 = *(const float4*)(hrow + idx + 4);
            bf16x8 v;
            v[0] = f2bf(p0.x); v[1] = f2bf(p0.y); v[2] = f2bf(p0.z); v[3] = f2bf(p0.w);
            v[4] = f2bf(p1.x); v[5] = f2bf(p1.y); v[6] = f2bf(p1.z); v[7] = f2bf(p1.w);
            *(bf16x8*)(&hid[row * 776 + col]) = v;
        }
    }
    __syncthreads();

    const short* abase = aT + (long)b * 96 * 256 * 8;
    f32x4 acc[2] = {};

#pragma unroll
    for (int ks = 0; ks < 24; ++ks) {
        const bf16x8 af = *(const bf16x8*)(&hid[l15 * 776 + ks * 32 + l4 * 8]);
#pragma unroll
        for (int nf = 0; nf < 2; ++nf) {
            const int w = w0 + wv * 32 + nf * 16 + l15;
            const bf16x8 bfv =
                *(const bf16x8*)(abase + ((long)(ks * 4 + l4) * 256 + w) * 8);
            acc[nf] = __builtin_amdgcn_mfma_f32_16x16x32_bf16(af, bfv, acc[nf], 0, 0, 0);
        }
    }

    // ---- exp + masked label-bucket accumulation ----
    const float inv_temper = 0.03608439182435161f;   // 1/sqrt(768)
    float s_loc[4][5];
#pragma unroll
    for (int i = 0; i < 4; ++i)
#pragma unroll
        for (int c = 0; c < 5; ++c) s_loc[i][c] = 0.f;

    const int* lab_base = label + (long)bl0 * WW;
#pragma unroll
    for (int nf = 0; nf < 2; ++nf) {
        const int w = w0 + wv * 32 + nf * 16 + l15;
#pragma unroll
        for (int i = 0; i < 4; ++i) {
            const int row = l4 * 4 + i;
            const int lv  = lab_base[row * WW + w];
            const float e = __expf(acc[nf][i] * inv_temper);
#pragma unroll
            for (int c = 1; c <= 5; ++c)
                s_loc[i][c - 1] += (lv == c) ? e : 0.f;
        }
    }
#pragma unroll
    for (int i = 0; i < 4; ++i) {
#pragma unroll
        for (int c = 0; c < 5; ++c) {
            float v = s_loc[i][c];
            v += __shfl_xor(v, 1);
            v += __shfl_xor(v, 2);
            v += __shfl_xor(v, 4);
            v += __shfl_xor(v, 8);
            s_loc[i][c] = v;
        }
    }
    if (l15 == 0) {
#pragma unroll
        for (int i = 0; i < 4; ++i)
#pragma unroll
            for (int c = 0; c < 5; ++c)
                s_lds[wv][l4 * 4 + i][c] = s_loc[i][c];
    }
    __syncthreads();
    if (t < 16) {
#pragma unroll
        for (int c = 0; c < 5; ++c) {
            const float s = s_lds[0][t][c] + s_lds[1][t][c] +
                            s_lds[2][t][c] + s_lds[3][t][c];
            s_part[(long)(bl0 + t) * 10 + whalf * 5 + c] = s;
        }
    }
}

// ---------------------------------------------------------------------------
// k3: output. 256 blocks x 256 thr, 8 rows each:
// o[row][h] = (sum_c s_c * emb_c[c][h]) / (sum_c s_c + 1e-10).
// ---------------------------------------------------------------------------
__global__ __launch_bounds__(256, 1) void k3_out(
    const float* __restrict__ s_part,   // [2048][10]
    const float* __restrict__ emb_c,    // [6][768]
    float*       __restrict__ out)      // [2048][768]
{
    const int t  = threadIdx.x;
    const int r0 = blockIdx.x * 8;

    float ecv[3][5];
#pragma unroll
    for (int q = 0; q < 3; ++q)
#pragma unroll
        for (int c = 0; c < 5; ++c)
            ecv[q][c] = emb_c[(c + 1) * HH + t + q * 256];

    for (int r = 0; r < 8; ++r) {
        const int row = r0 + r;
        float s[5], den = 1e-10f;
#pragma unroll
        for (int c = 0; c < 5; ++c) {
            s[c] = s_part[(long)row * 10 + c] + s_part[(long)row * 10 + 5 + c];
            den += s[c];
        }
        const float id = 1.0f / den;
        float* orow = out + (long)row * HH;
#pragma unroll
        for (int q = 0; q < 3; ++q) {
            const float v = s[0] * ecv[q][0] + s[1] * ecv[q][1] + s[2] * ecv[q][2] +
                            s[3] * ecv[q][3] + s[4] * ecv[q][4];
            orow[t + q * 256] = v * id;
        }
    }
}

extern "C" void kernel_launch(void* const* d_in, const int* in_sizes, int n_in,
                              void* d_out, int out_size, void* d_ws, size_t ws_size,
                              hipStream_t stream) {
    const int*   word_seq = (const int*)  d_in[0];
    const float* hidden   = (const float*)d_in[1];
    const int*   label    = (const int*)  d_in[2];
    const float* emb_a    = (const float*)d_in[3];
    const float* lin_w    = (const float*)d_in[4];
    const float* lin_b    = (const float*)d_in[5];
    const float* emb_c    = (const float*)d_in[6];
    float* out = (float*)d_out;

    short* aT     = (short*)d_ws;                       // 1.5 MB
    float* s_part = (float*)((char*)d_ws + 0x180000);   // 80 KB

    k1_a_gemm<<<dim3(192), 256, 0, stream>>>(word_seq, emb_a, lin_w, lin_b, aT);
    k2_attn<<<dim3(256), 256, 0, stream>>>(hidden, label, aT, s_part);
    k3_out<<<dim3(256), 256, 0, stream>>>(s_part, emb_c, out);
}